// Round 11
// baseline (5908.857 us; speedup 1.0000x reference)
//
#include <hip/hip_runtime.h>

// LSTM: B=64, T=512, D=1024, H=1024.
// v6 = v5 (best: fused 5627, total 5795) + xprj scan-consume layout.
//   xprj reordered to [t][wg(64)][scan-lane(256)][16 halves] so:
//   - scan xv read: 16 scattered 2B loads -> 2 coalesced b128 loads
//     (wave reads 2KB contiguous; removes ~2x sector over-fetch on the
//     256MB xprj stream and shortens the vmcnt tail ahead of the poll).
//   - gemm C-write: 64 scattered 2B stores -> 16 half4 (8B) stores.
//   Sync chain (poll/fence/h-loads/MFMA/store/publish) byte-identical to
//   v2/v5 (v3,v4 showed reordering it regresses).

typedef _Float16 half8 __attribute__((ext_vector_type(8)));
typedef _Float16 half4 __attribute__((ext_vector_type(4)));
typedef float floatx4 __attribute__((ext_vector_type(4)));

__device__ __forceinline__ void gll16(const void* g, void* l) {
  __builtin_amdgcn_global_load_lds(
      (const __attribute__((address_space(1))) unsigned int*)g,
      (__attribute__((address_space(3))) unsigned int*)l, 16, 0, 0);
}

__device__ __forceinline__ float sigm(float x) { return 1.f / (1.f + __expf(-x)); }
__device__ __forceinline__ float tanhfast(float x) { return 1.f - 2.f / (__expf(2.f * x) + 1.f); }

// ---------------- prep: convert xs (t-major rows), h0; zero flags/cnt/tot ----------------
__global__ void prep_ew(const float* __restrict__ xs, const float* __restrict__ h0,
                        _Float16* __restrict__ xs16, _Float16* __restrict__ hb0,
                        int* __restrict__ flags) {
  long gid = (long)blockIdx.x * blockDim.x + threadIdx.x;
  if (gid < 4194304) {
    const float4* p = (const float4*)xs + gid * 2;
    float4 u = p[0], w = p[1];
    half8 o;
    o[0] = (_Float16)u.x; o[1] = (_Float16)u.y; o[2] = (_Float16)u.z; o[3] = (_Float16)u.w;
    o[4] = (_Float16)w.x; o[5] = (_Float16)w.y; o[6] = (_Float16)w.z; o[7] = (_Float16)w.w;
    long e = gid * 8;
    long row = e >> 10;               // b*512 + t
    long b = row >> 9, t = row & 511;
    *(half8*)(xs16 + ((t << 6) + b) * 1024 + (e & 1023)) = o;  // row t*64+b
  } else if (gid < 4202496) {
    long j = gid - 4194304;
    const float4* p = (const float4*)h0 + j * 2;
    float4 u = p[0], w = p[1];
    half8 o;
    o[0] = (_Float16)u.x; o[1] = (_Float16)u.y; o[2] = (_Float16)u.z; o[3] = (_Float16)u.w;
    o[4] = (_Float16)w.x; o[5] = (_Float16)w.y; o[6] = (_Float16)w.z; o[7] = (_Float16)w.w;
    *(half8*)(hb0 + j * 8) = o;
  } else if (gid < 4203264) {
    flags[gid - 4202496] = 0;  // flags[0..255], cnt[256..511], tot[512], pad
  }
}

// ---------------- transpose [1024][4096] f32 -> [4096][1024] f16 ----------------
__global__ void transpose_k(const float* __restrict__ in, _Float16* __restrict__ outp) {
  __shared__ float s[32][33];
  int bx = blockIdx.x * 32, by = blockIdx.y * 32;
  int tx = threadIdx.x, ty = threadIdx.y;
#pragma unroll
  for (int k = 0; k < 32; k += 8)
    s[ty + k][tx] = in[(long)(by + ty + k) * 4096 + bx + tx];
  __syncthreads();
#pragma unroll
  for (int k = 0; k < 32; k += 8)
    outp[(long)(bx + ty + k) * 1024 + by + tx] = (_Float16)s[tx][ty + k];
}

// ---------------- fused: gemm1 workers + persistent scan ----------------
// xprj layout: [t(512)][wg(64)][lane(256)][16 halves], where lane = v*64+q*16+li
// and the 16 halves are [g(4)][r(4)] for scan row b=16v+4q+r, col 16wg+li.
__global__ __launch_bounds__(256, 1) void fused(const _Float16* __restrict__ xs16,
                                                const _Float16* __restrict__ wxt,
                                                _Float16* __restrict__ xprj,
                                                const _Float16* __restrict__ wht,
                                                const float* __restrict__ bias,
                                                const float* __restrict__ c0,
                                                _Float16* __restrict__ hbuf,
                                                int* __restrict__ flags,
                                                float* __restrict__ out) {
  __shared__ char smem[131072];
  const int tid = threadIdx.x;
  int* const cnt = flags + 256;
  int* const tot = flags + 512;

  if (blockIdx.x >= 64) {
    // ---------------- gemm1 tile ----------------
    _Float16* sA = (_Float16*)smem;
    _Float16* sB = (_Float16*)(smem + 8192);
    const int gid = blockIdx.x - 64;
    const int by = gid >> 5, bx = gid & 31;

    // pace: stay <= 48 steps (24 t-groups) ahead of the scan. Bounded wait
    // (timeout ~220us) -> liveness even under out-of-order dispatch.
    {
      int it = 0;
      for (;;) {
        int tp = __hip_atomic_load(&flags[0], __ATOMIC_RELAXED, __HIP_MEMORY_SCOPE_AGENT);
        if (tp >= 2 * by - 48 || ++it > 256) break;
        __builtin_amdgcn_s_sleep(64);
      }
    }

    const int w = tid >> 6, l = tid & 63, li = l & 15, q = l >> 4;
    const int wr = w >> 1, wc = w & 1;
    const int m0 = by * 128, n0 = bx * 128;
    floatx4 acc[4][4] = {};
    const _Float16* gA0 = xs16 + (long)(m0 + (w * 16 + li)) * 1024 + q * 8;
    const _Float16* gA1 = xs16 + (long)(m0 + ((4 + w) * 16 + li)) * 1024 + q * 8;
    const _Float16* gB0 = wxt + (long)(n0 + (w * 16 + li)) * 1024 + q * 8;
    const _Float16* gB1 = wxt + (long)(n0 + ((4 + w) * 16 + li)) * 1024 + q * 8;
    _Float16* lA0 = sA + (w * 64) * 8;
    _Float16* lA1 = sA + (256 + w * 64) * 8;
    _Float16* lB0 = sB + (w * 64) * 8;
    _Float16* lB1 = sB + (256 + w * 64) * 8;
    for (int k0 = 0; k0 < 1024; k0 += 32) {
      __syncthreads();
      gll16(gA0 + k0, lA0);
      gll16(gA1 + k0, lA1);
      gll16(gB0 + k0, lB0);
      gll16(gB1 + k0, lB1);
      __syncthreads();
      half8 af[4], bf[4];
      const half8* pA = (const half8*)sA;
      const half8* pB = (const half8*)sB;
#pragma unroll
      for (int i = 0; i < 4; i++) af[i] = pA[(wr * 4 + i) * 64 + l];
#pragma unroll
      for (int j = 0; j < 4; j++) bf[j] = pB[(wc * 4 + j) * 64 + l];
#pragma unroll
      for (int i = 0; i < 4; i++)
#pragma unroll
        for (int j = 0; j < 4; j++)
          acc[i][j] = __builtin_amdgcn_mfma_f32_16x16x32_f16(af[i], bf[j], acc[i][j], 0, 0, 0);
    }
    // C-write in scan-consume layout. For this tile: t = by*2+wr (fixed per
    // thread), scan row b = i*16 + q*4 + r, col = n0+wc*64+j*16+li.
    {
      const int t_ = by * 2 + wr;
#pragma unroll
      for (int i = 0; i < 4; i++) {
#pragma unroll
        for (int j = 0; j < 4; j++) {
          int n_ = n0 + wc * 64 + j * 16;       // li excluded (enters lane idx)
          int g_ = n_ >> 10, wg_ = (n_ & 1023) >> 4;
          half4 hv;
          hv[0] = (_Float16)acc[i][j][0];
          hv[1] = (_Float16)acc[i][j][1];
          hv[2] = (_Float16)acc[i][j][2];
          hv[3] = (_Float16)acc[i][j][3];
          *(half4*)(xprj + ((long)(t_ * 64 + wg_)) * 4096 +
                    (long)((i * 4 + q) * 16 + li) * 16 + g_ * 4) = hv;
        }
      }
    }
    __syncthreads();  // drains all threads' C stores (vmcnt 0 before barrier)
    if (tid == 0) {
      __builtin_amdgcn_fence(__ATOMIC_RELEASE, "agent");
      __hip_atomic_fetch_add(&cnt[by], 1, __ATOMIC_RELAXED, __HIP_MEMORY_SCOPE_AGENT);
      __hip_atomic_fetch_add(tot, 1, __ATOMIC_RELAXED, __HIP_MEMORY_SCOPE_AGENT);
    }
    return;
  }

  // ---------------- scan (chain identical to v2/v5; only xv load changed) ----------------
  _Float16* sW = (_Float16*)smem;  // [g(4)][kk(32)][lane(64)][8] = 128 KB
  const int wgid = blockIdx.x;     // 0..63
  const int v = tid >> 6;          // wave 0..3
  const int l = tid & 63, li = l & 15, q = l >> 4;
  const int ks = wgid * 16;

  // stage Wh^T slice into LDS once: 8192 x 16B chunks
#pragma unroll 4
  for (int i = 0; i < 32; i++) {
    int c = i * 256 + tid;
    int g = c >> 11, kk = (c >> 6) & 31;
    int cli = c & 15, cq = (c >> 4) & 3;
    gll16(wht + (long)((g << 10) + ks + cli) * 1024 + kk * 32 + cq * 8,
          sW + (long)(c - l) * 8);
  }
  float creg[4];
#pragma unroll
  for (int r = 0; r < 4; r++)
    creg[r] = c0[(long)(v * 16 + q * 4 + r) * 1024 + ks + li];
  float bs[4];
#pragma unroll
  for (int g = 0; g < 4; g++) bs[g] = bias[(g << 10) + ks + li];
  __syncthreads();  // sW resident; last barrier in the kernel

  const half8* pW = (const half8*)sW;
  const int fidx = 4 * l + v;  // lane l audits wg l, OWN wave-class only
  int xdone = 0;

  for (int t = 0; t < 512; t++) {
    // gate on xproj readiness for this 2-step group (cheap once gemm is ahead)
    if (!xdone && !(t & 1)) {
      const int nb = t >> 1;
      for (;;) {
        int cr = __hip_atomic_load(&cnt[nb], __ATOMIC_RELAXED, __HIP_MEMORY_SCOPE_AGENT);
        if (cr >= 32) break;
        __builtin_amdgcn_s_sleep(16);
      }
      xdone = (__hip_atomic_load(tot, __ATOMIC_RELAXED, __HIP_MEMORY_SCOPE_AGENT) >= 8192);
      __builtin_amdgcn_fence(__ATOMIC_ACQUIRE, "agent");
    }

    // prefetch this lane's xproj (2 coalesced b128 loads; hidden behind poll)
    const _Float16* xpt = xprj + ((long)t * 64 + wgid) * 4096 + (long)(v * 64 + l) * 16;
    half8 xv0 = *(const half8*)(xpt);
    half8 xv1 = *(const half8*)(xpt + 8);

    // one-shot poll of the 64 same-class wave-flags
    for (;;) {
      int f = __hip_atomic_load(&flags[fidx], __ATOMIC_RELAXED, __HIP_MEMORY_SCOPE_AGENT);
      if (__all(f >= t)) break;
      __builtin_amdgcn_s_sleep(1);
    }
    __builtin_amdgcn_fence(__ATOMIC_ACQUIRE, "workgroup");  // no hoisting of h loads

    // K-loop: acc[g] += h_t[16v..16v+16][:] @ Wh[:, g*1024+ks..+16]
    const _Float16* hrow = hbuf + (long)t * 65536 + (long)(v * 16 + li) * 1024 + q * 8;
    floatx4 acc[4] = {};
    half8 ap[8];
#pragma unroll
    for (int p = 0; p < 8; p++) ap[p] = *(const half8*)(hrow + p * 32);
#pragma unroll
    for (int kk = 0; kk < 32; kk++) {
      half8 a = ap[kk & 7];
#pragma unroll
      for (int g = 0; g < 4; g++)
        acc[g] = __builtin_amdgcn_mfma_f32_16x16x32_f16(a, pW[((g * 32 + kk) << 6) + l], acc[g], 0, 0, 0);
      if (kk < 24) ap[kk & 7] = *(const half8*)(hrow + (kk + 8) * 32);
    }

    // epilogue: lane-local gates for (b = 16v+q*4+r, col ks+li)
    // xv layout: xv0 = [g0 r0..3 | g1 r0..3], xv1 = [g2 r0..3 | g3 r0..3]
    _Float16* hnext = hbuf + (long)(t + 1) * 65536;
    float hval[4], cval[4];
#pragma unroll
    for (int r = 0; r < 4; r++) {
      float gi = acc[0][r] + (float)xv0[r] + bs[0];
      float gf = acc[1][r] + (float)xv0[4 + r] + bs[1];
      float gg = acc[2][r] + (float)xv1[r] + bs[2];
      float go = acc[3][r] + (float)xv1[4 + r] + bs[3];
      float cN = sigm(gf) * creg[r] + sigm(gi) * tanhfast(gg);
      creg[r] = cN;
      cval[r] = cN;
      float hN = sigm(go) * tanhfast(cN);
      hval[r] = hN;
      int b = v * 16 + q * 4 + r;
      unsigned short hu = __builtin_bit_cast(unsigned short, (_Float16)hN);
      __hip_atomic_store((unsigned short*)hnext + (long)b * 1024 + ks + li, hu,
                         __ATOMIC_RELAXED, __HIP_MEMORY_SCOPE_AGENT);
    }
    __builtin_amdgcn_s_waitcnt(0);  // drains ONLY the 4 h stores (rest consumed)
    if (l == 0)
      __hip_atomic_store(&flags[4 * wgid + v], t + 1, __ATOMIC_RELAXED, __HIP_MEMORY_SCOPE_AGENT);

    // slow ys (+ final cT/hT) stores AFTER publishing — off the critical path
#pragma unroll
    for (int r = 0; r < 4; r++) {
      int b = v * 16 + q * 4 + r;
      out[131072 + (long)b * 524288 + (long)t * 1024 + ks + li] = hval[r];
      if (t == 511) {
        out[(long)b * 1024 + ks + li] = cval[r];
        out[65536 + (long)b * 1024 + ks + li] = hval[r];
      }
    }
  }
}

// ---------------- host ----------------
extern "C" void kernel_launch(void* const* d_in, const int* in_sizes, int n_in,
                              void* d_out, int out_size, void* d_ws, size_t ws_size,
                              hipStream_t stream) {
  const float* c0 = (const float*)d_in[0];
  const float* h0 = (const float*)d_in[1];
  const float* xs = (const float*)d_in[2];
  const float* Wx = (const float*)d_in[3];
  const float* Wh = (const float*)d_in[4];
  const float* bias = (const float*)d_in[5];
  float* out = (float*)d_out;

  char* ws = (char*)d_ws;
  size_t off = 0;
  _Float16* xs16 = (_Float16*)(ws + off); off += 67108864;    // 32768x1024 f16 (t-major rows)
  _Float16* wxt  = (_Float16*)(ws + off); off += 8388608;     // 4096x1024 f16
  _Float16* wht  = (_Float16*)(ws + off); off += 8388608;     // 4096x1024 f16
  _Float16* xprj = (_Float16*)(ws + off); off += 268435456;   // [t][wg][lane][16] f16
  _Float16* hbuf = (_Float16*)(ws + off); off += 67239936;    // 513x64x1024 f16
  int* flags     = (int*)(ws + off);      off += 4096;        // flags[256], cnt[256], tot
  if (ws_size < off) return;

  prep_ew<<<16419, 256, 0, stream>>>(xs, h0, xs16, hbuf, flags);
  transpose_k<<<dim3(128, 32), dim3(32, 8), 0, stream>>>(Wx, wxt);
  transpose_k<<<dim3(128, 32), dim3(32, 8), 0, stream>>>(Wh, wht);
  fused<<<8256, 256, 0, stream>>>(xs16, wxt, xprj, wht, bias, c0, hbuf, flags, out);
}

// Round 13
// 5828.804 us; speedup vs baseline: 1.0137x; 1.0137x over previous
//
#include <hip/hip_runtime.h>

// LSTM: B=64, T=512, D=1024, H=1024.
// v7 = v5 scan/sync (best: fused 5627) + gate-planar xprj + merged front-end.
//   - xprj[g(4)][t(512)][wg(64)][lane(256)][r(4)] f16 (67MB/plane):
//     scan xv: 4x half4 coalesced loads (wave = 512B dense per gate) — keeps
//     v6's FETCH win (1078->686MB); gemm C-write: per (i,j) one dense 512B
//     wave store (lane->+8B, full sector fill) — kills v6's WRITE
//     amplification (538->~464MB) that cost +106us.
//   - prep_all: prep + both transposes in ONE kernel (block-range split);
//     3 serial launches (~170us) -> concurrent (~90us).
//   - scan sync chain byte-identical to v5 (v3/v4/v6 showed touching it or
//     its store patterns regresses).

typedef _Float16 half8 __attribute__((ext_vector_type(8)));
typedef _Float16 half4 __attribute__((ext_vector_type(4)));
typedef float floatx4 __attribute__((ext_vector_type(4)));

__device__ __forceinline__ void gll16(const void* g, void* l) {
  __builtin_amdgcn_global_load_lds(
      (const __attribute__((address_space(1))) unsigned int*)g,
      (__attribute__((address_space(3))) unsigned int*)l, 16, 0, 0);
}

__device__ __forceinline__ float sigm(float x) { return 1.f / (1.f + __expf(-x)); }
__device__ __forceinline__ float tanhfast(float x) { return 1.f - 2.f / (__expf(2.f * x) + 1.f); }

#define XPLANE 33554432L  // halves per xprj gate plane: 512*64*256*4

// ---------------- prep_all: xs convert + h0 convert + flags + both transposes ----------------
// blocks [0,16419): prep gids; [16419,20515): Wx transpose tiles; [20515,24611): Wh tiles.
__global__ void prep_all(const float* __restrict__ xs, const float* __restrict__ h0,
                         const float* __restrict__ Wx, const float* __restrict__ Wh,
                         _Float16* __restrict__ xs16, _Float16* __restrict__ hb0,
                         _Float16* __restrict__ wxt, _Float16* __restrict__ wht,
                         int* __restrict__ flags) {
  const int tid = threadIdx.x;
  if (blockIdx.x < 16419) {
    long gid = (long)blockIdx.x * 256 + tid;
    if (gid < 4194304) {
      const float4* p = (const float4*)xs + gid * 2;
      float4 u = p[0], w = p[1];
      half8 o;
      o[0] = (_Float16)u.x; o[1] = (_Float16)u.y; o[2] = (_Float16)u.z; o[3] = (_Float16)u.w;
      o[4] = (_Float16)w.x; o[5] = (_Float16)w.y; o[6] = (_Float16)w.z; o[7] = (_Float16)w.w;
      long e = gid * 8;
      long row = e >> 10;               // b*512 + t
      long b = row >> 9, t = row & 511;
      *(half8*)(xs16 + ((t << 6) + b) * 1024 + (e & 1023)) = o;  // row t*64+b
    } else if (gid < 4202496) {
      long j = gid - 4194304;
      const float4* p = (const float4*)h0 + j * 2;
      float4 u = p[0], w = p[1];
      half8 o;
      o[0] = (_Float16)u.x; o[1] = (_Float16)u.y; o[2] = (_Float16)u.z; o[3] = (_Float16)u.w;
      o[4] = (_Float16)w.x; o[5] = (_Float16)w.y; o[6] = (_Float16)w.z; o[7] = (_Float16)w.w;
      *(half8*)(hb0 + j * 8) = o;
    } else if (gid < 4203264) {
      flags[gid - 4202496] = 0;  // flags[0..255], cnt[256..511], tot[512], pad
    }
    return;
  }
  // transpose tile: [1024][4096] f32 -> [4096][1024] f16
  __shared__ float s[32][33];
  int tb = blockIdx.x - 16419;
  const float* in = Wx;
  _Float16* outp = wxt;
  if (tb >= 4096) { tb -= 4096; in = Wh; outp = wht; }
  int bx = (tb & 127) * 32, by = (tb >> 7) * 32;
  int tx = tid & 31, ty = tid >> 5;  // 32 x 8
#pragma unroll
  for (int k = 0; k < 32; k += 8)
    s[ty + k][tx] = in[(long)(by + ty + k) * 4096 + bx + tx];
  __syncthreads();
#pragma unroll
  for (int k = 0; k < 32; k += 8)
    outp[(long)(bx + ty + k) * 1024 + by + tx] = (_Float16)s[tx][ty + k];
}

// ---------------- fused: gemm1 workers + persistent scan ----------------
__global__ __launch_bounds__(256, 1) void fused(const _Float16* __restrict__ xs16,
                                                const _Float16* __restrict__ wxt,
                                                _Float16* __restrict__ xprj,
                                                const _Float16* __restrict__ wht,
                                                const float* __restrict__ bias,
                                                const float* __restrict__ c0,
                                                _Float16* __restrict__ hbuf,
                                                int* __restrict__ flags,
                                                float* __restrict__ out) {
  __shared__ char smem[131072];
  const int tid = threadIdx.x;
  int* const cnt = flags + 256;
  int* const tot = flags + 512;

  if (blockIdx.x >= 64) {
    // ---------------- gemm1 tile ----------------
    _Float16* sA = (_Float16*)smem;
    _Float16* sB = (_Float16*)(smem + 8192);
    const int gid = blockIdx.x - 64;
    const int by = gid >> 5, bx = gid & 31;

    // pace: stay <= 48 steps (24 t-groups) ahead of the scan. Bounded wait
    // (timeout ~220us) -> liveness even under out-of-order dispatch.
    {
      int it = 0;
      for (;;) {
        int tp = __hip_atomic_load(&flags[0], __ATOMIC_RELAXED, __HIP_MEMORY_SCOPE_AGENT);
        if (tp >= 2 * by - 48 || ++it > 256) break;
        __builtin_amdgcn_s_sleep(64);
      }
    }

    const int w = tid >> 6, l = tid & 63, li = l & 15, q = l >> 4;
    const int wr = w >> 1, wc = w & 1;
    const int m0 = by * 128, n0 = bx * 128;
    floatx4 acc[4][4] = {};
    const _Float16* gA0 = xs16 + (long)(m0 + (w * 16 + li)) * 1024 + q * 8;
    const _Float16* gA1 = xs16 + (long)(m0 + ((4 + w) * 16 + li)) * 1024 + q * 8;
    const _Float16* gB0 = wxt + (long)(n0 + (w * 16 + li)) * 1024 + q * 8;
    const _Float16* gB1 = wxt + (long)(n0 + ((4 + w) * 16 + li)) * 1024 + q * 8;
    _Float16* lA0 = sA + (w * 64) * 8;
    _Float16* lA1 = sA + (256 + w * 64) * 8;
    _Float16* lB0 = sB + (w * 64) * 8;
    _Float16* lB1 = sB + (256 + w * 64) * 8;
    for (int k0 = 0; k0 < 1024; k0 += 32) {
      __syncthreads();
      gll16(gA0 + k0, lA0);
      gll16(gA1 + k0, lA1);
      gll16(gB0 + k0, lB0);
      gll16(gB1 + k0, lB1);
      __syncthreads();
      half8 af[4], bf[4];
      const half8* pA = (const half8*)sA;
      const half8* pB = (const half8*)sB;
#pragma unroll
      for (int i = 0; i < 4; i++) af[i] = pA[(wr * 4 + i) * 64 + l];
#pragma unroll
      for (int j = 0; j < 4; j++) bf[j] = pB[(wc * 4 + j) * 64 + l];
#pragma unroll
      for (int i = 0; i < 4; i++)
#pragma unroll
        for (int j = 0; j < 4; j++)
          acc[i][j] = __builtin_amdgcn_mfma_f32_16x16x32_f16(af[i], bf[j], acc[i][j], 0, 0, 0);
    }
    // C-write, gate-planar scan-consume layout. t = by*2+wr fixed per thread;
    // per (i,j): one dense 512B wave store into plane g_.
    {
      const int t_ = by * 2 + wr;
#pragma unroll
      for (int i = 0; i < 4; i++) {
#pragma unroll
        for (int j = 0; j < 4; j++) {
          int n_ = n0 + wc * 64 + j * 16;       // li excluded (enters lane idx)
          int g_ = n_ >> 10, wg_ = (n_ & 1023) >> 4;
          half4 hv;
          hv[0] = (_Float16)acc[i][j][0];
          hv[1] = (_Float16)acc[i][j][1];
          hv[2] = (_Float16)acc[i][j][2];
          hv[3] = (_Float16)acc[i][j][3];
          *(half4*)(xprj + (long)g_ * XPLANE +
                    (((long)t_ * 64 + wg_) * 256 + (i * 4 + q) * 16 + li) * 4) = hv;
        }
      }
    }
    __syncthreads();  // drains all threads' C stores (vmcnt 0 before barrier)
    if (tid == 0) {
      __builtin_amdgcn_fence(__ATOMIC_RELEASE, "agent");
      __hip_atomic_fetch_add(&cnt[by], 1, __ATOMIC_RELAXED, __HIP_MEMORY_SCOPE_AGENT);
      __hip_atomic_fetch_add(tot, 1, __ATOMIC_RELAXED, __HIP_MEMORY_SCOPE_AGENT);
    }
    return;
  }

  // ---------------- scan (chain identical to v2/v5; only xv load changed) ----------------
  _Float16* sW = (_Float16*)smem;  // [g(4)][kk(32)][lane(64)][8] = 128 KB
  const int wgid = blockIdx.x;     // 0..63
  const int v = tid >> 6;          // wave 0..3
  const int l = tid & 63, li = l & 15, q = l >> 4;
  const int ks = wgid * 16;

  // stage Wh^T slice into LDS once: 8192 x 16B chunks
#pragma unroll 4
  for (int i = 0; i < 32; i++) {
    int c = i * 256 + tid;
    int g = c >> 11, kk = (c >> 6) & 31;
    int cli = c & 15, cq = (c >> 4) & 3;
    gll16(wht + (long)((g << 10) + ks + cli) * 1024 + kk * 32 + cq * 8,
          sW + (long)(c - l) * 8);
  }
  float creg[4];
#pragma unroll
  for (int r = 0; r < 4; r++)
    creg[r] = c0[(long)(v * 16 + q * 4 + r) * 1024 + ks + li];
  float bs[4];
#pragma unroll
  for (int g = 0; g < 4; g++) bs[g] = bias[(g << 10) + ks + li];
  __syncthreads();  // sW resident; last barrier in the kernel

  const half8* pW = (const half8*)sW;
  const int fidx = 4 * l + v;  // lane l audits wg l, OWN wave-class only
  int xdone = 0;

  for (int t = 0; t < 512; t++) {
    // gate on xproj readiness for this 2-step group (cheap once gemm is ahead)
    if (!xdone && !(t & 1)) {
      const int nb = t >> 1;
      for (;;) {
        int cr = __hip_atomic_load(&cnt[nb], __ATOMIC_RELAXED, __HIP_MEMORY_SCOPE_AGENT);
        if (cr >= 32) break;
        __builtin_amdgcn_s_sleep(16);
      }
      xdone = (__hip_atomic_load(tot, __ATOMIC_RELAXED, __HIP_MEMORY_SCOPE_AGENT) >= 8192);
      __builtin_amdgcn_fence(__ATOMIC_ACQUIRE, "agent");
    }

    // prefetch this lane's xproj: 4 coalesced half4 loads (hidden behind poll)
    const long xbase = (((long)t * 64 + wgid) * 256 + v * 64 + l) * 4;
    half4 xg0 = *(const half4*)(xprj + 0 * XPLANE + xbase);
    half4 xg1 = *(const half4*)(xprj + 1 * XPLANE + xbase);
    half4 xg2 = *(const half4*)(xprj + 2 * XPLANE + xbase);
    half4 xg3 = *(const half4*)(xprj + 3 * XPLANE + xbase);

    // one-shot poll of the 64 same-class wave-flags
    for (;;) {
      int f = __hip_atomic_load(&flags[fidx], __ATOMIC_RELAXED, __HIP_MEMORY_SCOPE_AGENT);
      if (__all(f >= t)) break;
      __builtin_amdgcn_s_sleep(1);
    }
    __builtin_amdgcn_fence(__ATOMIC_ACQUIRE, "workgroup");  // no hoisting of h loads

    // K-loop: acc[g] += h_t[16v..16v+16][:] @ Wh[:, g*1024+ks..+16]
    const _Float16* hrow = hbuf + (long)t * 65536 + (long)(v * 16 + li) * 1024 + q * 8;
    floatx4 acc[4] = {};
    half8 ap[8];
#pragma unroll
    for (int p = 0; p < 8; p++) ap[p] = *(const half8*)(hrow + p * 32);
#pragma unroll
    for (int kk = 0; kk < 32; kk++) {
      half8 a = ap[kk & 7];
#pragma unroll
      for (int g = 0; g < 4; g++)
        acc[g] = __builtin_amdgcn_mfma_f32_16x16x32_f16(a, pW[((g * 32 + kk) << 6) + l], acc[g], 0, 0, 0);
      if (kk < 24) ap[kk & 7] = *(const half8*)(hrow + (kk + 8) * 32);
    }

    // epilogue: lane-local gates for (b = 16v+q*4+r, col ks+li)
    _Float16* hnext = hbuf + (long)(t + 1) * 65536;
    float hval[4], cval[4];
#pragma unroll
    for (int r = 0; r < 4; r++) {
      float gi = acc[0][r] + (float)xg0[r] + bs[0];
      float gf = acc[1][r] + (float)xg1[r] + bs[1];
      float gg = acc[2][r] + (float)xg2[r] + bs[2];
      float go = acc[3][r] + (float)xg3[r] + bs[3];
      float cN = sigm(gf) * creg[r] + sigm(gi) * tanhfast(gg);
      creg[r] = cN;
      cval[r] = cN;
      float hN = sigm(go) * tanhfast(cN);
      hval[r] = hN;
      int b = v * 16 + q * 4 + r;
      unsigned short hu = __builtin_bit_cast(unsigned short, (_Float16)hN);
      __hip_atomic_store((unsigned short*)hnext + (long)b * 1024 + ks + li, hu,
                         __ATOMIC_RELAXED, __HIP_MEMORY_SCOPE_AGENT);
    }
    __builtin_amdgcn_s_waitcnt(0);  // drains ONLY the 4 h stores (rest consumed)
    if (l == 0)
      __hip_atomic_store(&flags[4 * wgid + v], t + 1, __ATOMIC_RELAXED, __HIP_MEMORY_SCOPE_AGENT);

    // slow ys (+ final cT/hT) stores AFTER publishing — off the critical path
#pragma unroll
    for (int r = 0; r < 4; r++) {
      int b = v * 16 + q * 4 + r;
      out[131072 + (long)b * 524288 + (long)t * 1024 + ks + li] = hval[r];
      if (t == 511) {
        out[(long)b * 1024 + ks + li] = cval[r];
        out[65536 + (long)b * 1024 + ks + li] = hval[r];
      }
    }
  }
}

// ---------------- host ----------------
extern "C" void kernel_launch(void* const* d_in, const int* in_sizes, int n_in,
                              void* d_out, int out_size, void* d_ws, size_t ws_size,
                              hipStream_t stream) {
  const float* c0 = (const float*)d_in[0];
  const float* h0 = (const float*)d_in[1];
  const float* xs = (const float*)d_in[2];
  const float* Wx = (const float*)d_in[3];
  const float* Wh = (const float*)d_in[4];
  const float* bias = (const float*)d_in[5];
  float* out = (float*)d_out;

  char* ws = (char*)d_ws;
  size_t off = 0;
  _Float16* xs16 = (_Float16*)(ws + off); off += 67108864;    // 32768x1024 f16 (t-major rows)
  _Float16* wxt  = (_Float16*)(ws + off); off += 8388608;     // 4096x1024 f16
  _Float16* wht  = (_Float16*)(ws + off); off += 8388608;     // 4096x1024 f16
  _Float16* xprj = (_Float16*)(ws + off); off += 268435456;   // [g][t][wg][lane][4] f16
  _Float16* hbuf = (_Float16*)(ws + off); off += 67239936;    // 513x64x1024 f16
  int* flags     = (int*)(ws + off);      off += 4096;        // flags[256], cnt[256], tot
  if (ws_size < off) return;

  prep_all<<<24611, 256, 0, stream>>>(xs, h0, Wx, Wh, xs16, hbuf, wxt, wht, flags);
  fused<<<8256, 256, 0, stream>>>(xs16, wxt, xprj, wht, bias, c0, hbuf, flags, out);
}

// Round 14
// 5815.936 us; speedup vs baseline: 1.0160x; 1.0022x over previous
//
#include <hip/hip_runtime.h>

// LSTM: B=64, T=512, D=1024, H=1024.
// v8 = v7 fused (gate-planar xprj, fused 5617) with:
//   - front-end reverted to v5's 3 separate kernels (merged prep_all measured
//     211us vs 168us split -> revert, -43us)
//   - h-load pipeline 8 -> 16 deep ROLLING (same proven rolling idiom as v2's
//     8-deep, just doubled; v3's failure was issue-all-upfront ap[32], a
//     different structure). Halves h-load serialization: 32/8x700cy=1.2us ->
//     32/16x700cy=0.6us per step. VGPR +32 (~164), occupancy LDS-pinned so free.
//   - scan sync chain + pacing byte-identical to v5/v7.

typedef _Float16 half8 __attribute__((ext_vector_type(8)));
typedef _Float16 half4 __attribute__((ext_vector_type(4)));
typedef float floatx4 __attribute__((ext_vector_type(4)));

__device__ __forceinline__ void gll16(const void* g, void* l) {
  __builtin_amdgcn_global_load_lds(
      (const __attribute__((address_space(1))) unsigned int*)g,
      (__attribute__((address_space(3))) unsigned int*)l, 16, 0, 0);
}

__device__ __forceinline__ float sigm(float x) { return 1.f / (1.f + __expf(-x)); }
__device__ __forceinline__ float tanhfast(float x) { return 1.f - 2.f / (__expf(2.f * x) + 1.f); }

#define XPLANE 33554432L  // halves per xprj gate plane: 512*64*256*4

// ---------------- prep: convert xs (t-major rows), h0; zero flags/cnt/tot ----------------
__global__ void prep_ew(const float* __restrict__ xs, const float* __restrict__ h0,
                        _Float16* __restrict__ xs16, _Float16* __restrict__ hb0,
                        int* __restrict__ flags) {
  long gid = (long)blockIdx.x * blockDim.x + threadIdx.x;
  if (gid < 4194304) {
    const float4* p = (const float4*)xs + gid * 2;
    float4 u = p[0], w = p[1];
    half8 o;
    o[0] = (_Float16)u.x; o[1] = (_Float16)u.y; o[2] = (_Float16)u.z; o[3] = (_Float16)u.w;
    o[4] = (_Float16)w.x; o[5] = (_Float16)w.y; o[6] = (_Float16)w.z; o[7] = (_Float16)w.w;
    long e = gid * 8;
    long row = e >> 10;               // b*512 + t
    long b = row >> 9, t = row & 511;
    *(half8*)(xs16 + ((t << 6) + b) * 1024 + (e & 1023)) = o;  // row t*64+b
  } else if (gid < 4202496) {
    long j = gid - 4194304;
    const float4* p = (const float4*)h0 + j * 2;
    float4 u = p[0], w = p[1];
    half8 o;
    o[0] = (_Float16)u.x; o[1] = (_Float16)u.y; o[2] = (_Float16)u.z; o[3] = (_Float16)u.w;
    o[4] = (_Float16)w.x; o[5] = (_Float16)w.y; o[6] = (_Float16)w.z; o[7] = (_Float16)w.w;
    *(half8*)(hb0 + j * 8) = o;
  } else if (gid < 4203264) {
    flags[gid - 4202496] = 0;  // flags[0..255], cnt[256..511], tot[512], pad
  }
}

// ---------------- transpose [1024][4096] f32 -> [4096][1024] f16 ----------------
__global__ void transpose_k(const float* __restrict__ in, _Float16* __restrict__ outp) {
  __shared__ float s[32][33];
  int bx = blockIdx.x * 32, by = blockIdx.y * 32;
  int tx = threadIdx.x, ty = threadIdx.y;
#pragma unroll
  for (int k = 0; k < 32; k += 8)
    s[ty + k][tx] = in[(long)(by + ty + k) * 4096 + bx + tx];
  __syncthreads();
#pragma unroll
  for (int k = 0; k < 32; k += 8)
    outp[(long)(bx + ty + k) * 1024 + by + tx] = (_Float16)s[tx][ty + k];
}

// ---------------- fused: gemm1 workers + persistent scan ----------------
__global__ __launch_bounds__(256, 1) void fused(const _Float16* __restrict__ xs16,
                                                const _Float16* __restrict__ wxt,
                                                _Float16* __restrict__ xprj,
                                                const _Float16* __restrict__ wht,
                                                const float* __restrict__ bias,
                                                const float* __restrict__ c0,
                                                _Float16* __restrict__ hbuf,
                                                int* __restrict__ flags,
                                                float* __restrict__ out) {
  __shared__ char smem[131072];
  const int tid = threadIdx.x;
  int* const cnt = flags + 256;
  int* const tot = flags + 512;

  if (blockIdx.x >= 64) {
    // ---------------- gemm1 tile ----------------
    _Float16* sA = (_Float16*)smem;
    _Float16* sB = (_Float16*)(smem + 8192);
    const int gid = blockIdx.x - 64;
    const int by = gid >> 5, bx = gid & 31;

    // pace: stay <= 48 steps (24 t-groups) ahead of the scan. Bounded wait
    // (timeout) -> liveness even under out-of-order dispatch.
    {
      int it = 0;
      for (;;) {
        int tp = __hip_atomic_load(&flags[0], __ATOMIC_RELAXED, __HIP_MEMORY_SCOPE_AGENT);
        if (tp >= 2 * by - 48 || ++it > 256) break;
        __builtin_amdgcn_s_sleep(64);
      }
    }

    const int w = tid >> 6, l = tid & 63, li = l & 15, q = l >> 4;
    const int wr = w >> 1, wc = w & 1;
    const int m0 = by * 128, n0 = bx * 128;
    floatx4 acc[4][4] = {};
    const _Float16* gA0 = xs16 + (long)(m0 + (w * 16 + li)) * 1024 + q * 8;
    const _Float16* gA1 = xs16 + (long)(m0 + ((4 + w) * 16 + li)) * 1024 + q * 8;
    const _Float16* gB0 = wxt + (long)(n0 + (w * 16 + li)) * 1024 + q * 8;
    const _Float16* gB1 = wxt + (long)(n0 + ((4 + w) * 16 + li)) * 1024 + q * 8;
    _Float16* lA0 = sA + (w * 64) * 8;
    _Float16* lA1 = sA + (256 + w * 64) * 8;
    _Float16* lB0 = sB + (w * 64) * 8;
    _Float16* lB1 = sB + (256 + w * 64) * 8;
    for (int k0 = 0; k0 < 1024; k0 += 32) {
      __syncthreads();
      gll16(gA0 + k0, lA0);
      gll16(gA1 + k0, lA1);
      gll16(gB0 + k0, lB0);
      gll16(gB1 + k0, lB1);
      __syncthreads();
      half8 af[4], bf[4];
      const half8* pA = (const half8*)sA;
      const half8* pB = (const half8*)sB;
#pragma unroll
      for (int i = 0; i < 4; i++) af[i] = pA[(wr * 4 + i) * 64 + l];
#pragma unroll
      for (int j = 0; j < 4; j++) bf[j] = pB[(wc * 4 + j) * 64 + l];
#pragma unroll
      for (int i = 0; i < 4; i++)
#pragma unroll
        for (int j = 0; j < 4; j++)
          acc[i][j] = __builtin_amdgcn_mfma_f32_16x16x32_f16(af[i], bf[j], acc[i][j], 0, 0, 0);
    }
    // C-write, gate-planar scan-consume layout. t = by*2+wr fixed per thread;
    // per (i,j): one dense 512B wave store into plane g_.
    {
      const int t_ = by * 2 + wr;
#pragma unroll
      for (int i = 0; i < 4; i++) {
#pragma unroll
        for (int j = 0; j < 4; j++) {
          int n_ = n0 + wc * 64 + j * 16;       // li excluded (enters lane idx)
          int g_ = n_ >> 10, wg_ = (n_ & 1023) >> 4;
          half4 hv;
          hv[0] = (_Float16)acc[i][j][0];
          hv[1] = (_Float16)acc[i][j][1];
          hv[2] = (_Float16)acc[i][j][2];
          hv[3] = (_Float16)acc[i][j][3];
          *(half4*)(xprj + (long)g_ * XPLANE +
                    (((long)t_ * 64 + wg_) * 256 + (i * 4 + q) * 16 + li) * 4) = hv;
        }
      }
    }
    __syncthreads();  // drains all threads' C stores (vmcnt 0 before barrier)
    if (tid == 0) {
      __builtin_amdgcn_fence(__ATOMIC_RELEASE, "agent");
      __hip_atomic_fetch_add(&cnt[by], 1, __ATOMIC_RELAXED, __HIP_MEMORY_SCOPE_AGENT);
      __hip_atomic_fetch_add(tot, 1, __ATOMIC_RELAXED, __HIP_MEMORY_SCOPE_AGENT);
    }
    return;
  }

  // ---------------- scan (sync chain identical to v5/v7; h-pipe 16-deep) ----------------
  _Float16* sW = (_Float16*)smem;  // [g(4)][kk(32)][lane(64)][8] = 128 KB
  const int wgid = blockIdx.x;     // 0..63
  const int v = tid >> 6;          // wave 0..3
  const int l = tid & 63, li = l & 15, q = l >> 4;
  const int ks = wgid * 16;

  // stage Wh^T slice into LDS once: 8192 x 16B chunks
#pragma unroll 4
  for (int i = 0; i < 32; i++) {
    int c = i * 256 + tid;
    int g = c >> 11, kk = (c >> 6) & 31;
    int cli = c & 15, cq = (c >> 4) & 3;
    gll16(wht + (long)((g << 10) + ks + cli) * 1024 + kk * 32 + cq * 8,
          sW + (long)(c - l) * 8);
  }
  float creg[4];
#pragma unroll
  for (int r = 0; r < 4; r++)
    creg[r] = c0[(long)(v * 16 + q * 4 + r) * 1024 + ks + li];
  float bs[4];
#pragma unroll
  for (int g = 0; g < 4; g++) bs[g] = bias[(g << 10) + ks + li];
  __syncthreads();  // sW resident; last barrier in the kernel

  const half8* pW = (const half8*)sW;
  const int fidx = 4 * l + v;  // lane l audits wg l, OWN wave-class only
  int xdone = 0;

  for (int t = 0; t < 512; t++) {
    // gate on xproj readiness for this 2-step group (cheap once gemm is ahead)
    if (!xdone && !(t & 1)) {
      const int nb = t >> 1;
      for (;;) {
        int cr = __hip_atomic_load(&cnt[nb], __ATOMIC_RELAXED, __HIP_MEMORY_SCOPE_AGENT);
        if (cr >= 32) break;
        __builtin_amdgcn_s_sleep(16);
      }
      xdone = (__hip_atomic_load(tot, __ATOMIC_RELAXED, __HIP_MEMORY_SCOPE_AGENT) >= 8192);
      __builtin_amdgcn_fence(__ATOMIC_ACQUIRE, "agent");
    }

    // prefetch this lane's xproj: 4 coalesced half4 loads (hidden behind poll)
    const long xbase = (((long)t * 64 + wgid) * 256 + v * 64 + l) * 4;
    half4 xg0 = *(const half4*)(xprj + 0 * XPLANE + xbase);
    half4 xg1 = *(const half4*)(xprj + 1 * XPLANE + xbase);
    half4 xg2 = *(const half4*)(xprj + 2 * XPLANE + xbase);
    half4 xg3 = *(const half4*)(xprj + 3 * XPLANE + xbase);

    // one-shot poll of the 64 same-class wave-flags
    for (;;) {
      int f = __hip_atomic_load(&flags[fidx], __ATOMIC_RELAXED, __HIP_MEMORY_SCOPE_AGENT);
      if (__all(f >= t)) break;
      __builtin_amdgcn_s_sleep(1);
    }
    __builtin_amdgcn_fence(__ATOMIC_ACQUIRE, "workgroup");  // no hoisting of h loads

    // K-loop: acc[g] += h_t[16v..16v+16][:] @ Wh[:, g*1024+ks..+16]
    // 16-deep ROLLING h pipeline (same idiom as proven 8-deep, doubled)
    const _Float16* hrow = hbuf + (long)t * 65536 + (long)(v * 16 + li) * 1024 + q * 8;
    floatx4 acc[4] = {};
    half8 ap[16];
#pragma unroll
    for (int p = 0; p < 16; p++) ap[p] = *(const half8*)(hrow + p * 32);
#pragma unroll
    for (int kk = 0; kk < 32; kk++) {
      half8 a = ap[kk & 15];
#pragma unroll
      for (int g = 0; g < 4; g++)
        acc[g] = __builtin_amdgcn_mfma_f32_16x16x32_f16(a, pW[((g * 32 + kk) << 6) + l], acc[g], 0, 0, 0);
      if (kk < 16) ap[kk & 15] = *(const half8*)(hrow + (kk + 16) * 32);
    }

    // epilogue: lane-local gates for (b = 16v+q*4+r, col ks+li)
    _Float16* hnext = hbuf + (long)(t + 1) * 65536;
    float hval[4], cval[4];
#pragma unroll
    for (int r = 0; r < 4; r++) {
      float gi = acc[0][r] + (float)xg0[r] + bs[0];
      float gf = acc[1][r] + (float)xg1[r] + bs[1];
      float gg = acc[2][r] + (float)xg2[r] + bs[2];
      float go = acc[3][r] + (float)xg3[r] + bs[3];
      float cN = sigm(gf) * creg[r] + sigm(gi) * tanhfast(gg);
      creg[r] = cN;
      cval[r] = cN;
      float hN = sigm(go) * tanhfast(cN);
      hval[r] = hN;
      int b = v * 16 + q * 4 + r;
      unsigned short hu = __builtin_bit_cast(unsigned short, (_Float16)hN);
      __hip_atomic_store((unsigned short*)hnext + (long)b * 1024 + ks + li, hu,
                         __ATOMIC_RELAXED, __HIP_MEMORY_SCOPE_AGENT);
    }
    __builtin_amdgcn_s_waitcnt(0);  // drains ONLY the 4 h stores (rest consumed)
    if (l == 0)
      __hip_atomic_store(&flags[4 * wgid + v], t + 1, __ATOMIC_RELAXED, __HIP_MEMORY_SCOPE_AGENT);

    // slow ys (+ final cT/hT) stores AFTER publishing — off the critical path
#pragma unroll
    for (int r = 0; r < 4; r++) {
      int b = v * 16 + q * 4 + r;
      out[131072 + (long)b * 524288 + (long)t * 1024 + ks + li] = hval[r];
      if (t == 511) {
        out[(long)b * 1024 + ks + li] = cval[r];
        out[65536 + (long)b * 1024 + ks + li] = hval[r];
      }
    }
  }
}

// ---------------- host ----------------
extern "C" void kernel_launch(void* const* d_in, const int* in_sizes, int n_in,
                              void* d_out, int out_size, void* d_ws, size_t ws_size,
                              hipStream_t stream) {
  const float* c0 = (const float*)d_in[0];
  const float* h0 = (const float*)d_in[1];
  const float* xs = (const float*)d_in[2];
  const float* Wx = (const float*)d_in[3];
  const float* Wh = (const float*)d_in[4];
  const float* bias = (const float*)d_in[5];
  float* out = (float*)d_out;

  char* ws = (char*)d_ws;
  size_t off = 0;
  _Float16* xs16 = (_Float16*)(ws + off); off += 67108864;    // 32768x1024 f16 (t-major rows)
  _Float16* wxt  = (_Float16*)(ws + off); off += 8388608;     // 4096x1024 f16
  _Float16* wht  = (_Float16*)(ws + off); off += 8388608;     // 4096x1024 f16
  _Float16* xprj = (_Float16*)(ws + off); off += 268435456;   // [g][t][wg][lane][4] f16
  _Float16* hbuf = (_Float16*)(ws + off); off += 67239936;    // 513x64x1024 f16
  int* flags     = (int*)(ws + off);      off += 4096;        // flags[256], cnt[256], tot
  if (ws_size < off) return;

  prep_ew<<<16419, 256, 0, stream>>>(xs, h0, xs16, hbuf, flags);
  transpose_k<<<dim3(128, 32), dim3(32, 8), 0, stream>>>(Wx, wxt);
  transpose_k<<<dim3(128, 32), dim3(32, 8), 0, stream>>>(Wh, wht);
  fused<<<8256, 256, 0, stream>>>(xs16, wxt, xprj, wht, bias, c0, hbuf, flags, out);
}

// Round 15
// 5032.298 us; speedup vs baseline: 1.1742x; 1.1557x over previous
//
#include <hip/hip_runtime.h>

// LSTM: B=64, T=512, D=1024, H=1024.
// v9 = v8 base (gate-planar xprj, 3-kernel front-end) with:
//   - h-pipe back to PROVEN 8-deep rolling (v8's 16-deep: VGPR stayed 132 ->
//     compiler sinks relaxed loads to just-before-use; deepening is dead).
//   - FLAGS SPREAD: each wave-flag/cnt gets its own 64B cache line
//     (index*16). Hypothesis: 256 flags in 1KB = 16 lines hammered by
//     ~10^4 agent-scope poll loads/us + 256 stores/step -> coherence-point
//     contention is the unmodeled ~6us/step. Spreading changes ONLY address
//     arithmetic; sync structure/order byte-identical to v5/v7/v8.

typedef _Float16 half8 __attribute__((ext_vector_type(8)));
typedef _Float16 half4 __attribute__((ext_vector_type(4)));
typedef float floatx4 __attribute__((ext_vector_type(4)));

__device__ __forceinline__ void gll16(const void* g, void* l) {
  __builtin_amdgcn_global_load_lds(
      (const __attribute__((address_space(1))) unsigned int*)g,
      (__attribute__((address_space(3))) unsigned int*)l, 16, 0, 0);
}

__device__ __forceinline__ float sigm(float x) { return 1.f / (1.f + __expf(-x)); }
__device__ __forceinline__ float tanhfast(float x) { return 1.f - 2.f / (__expf(2.f * x) + 1.f); }

#define XPLANE 33554432L  // halves per xprj gate plane: 512*64*256*4
// flags[i*16] : wave-flags (i=0..255), one 64B line each (16KB)
// cnt = flags+4096 : cnt[nb*16] (nb=0..255), one line each (16KB)
// tot = flags+8192 : single counter

// ---------------- prep: convert xs (t-major rows), h0; zero flags/cnt/tot ----------------
__global__ void prep_ew(const float* __restrict__ xs, const float* __restrict__ h0,
                        _Float16* __restrict__ xs16, _Float16* __restrict__ hb0,
                        int* __restrict__ flags) {
  long gid = (long)blockIdx.x * blockDim.x + threadIdx.x;
  if (gid < 4194304) {
    const float4* p = (const float4*)xs + gid * 2;
    float4 u = p[0], w = p[1];
    half8 o;
    o[0] = (_Float16)u.x; o[1] = (_Float16)u.y; o[2] = (_Float16)u.z; o[3] = (_Float16)u.w;
    o[4] = (_Float16)w.x; o[5] = (_Float16)w.y; o[6] = (_Float16)w.z; o[7] = (_Float16)w.w;
    long e = gid * 8;
    long row = e >> 10;               // b*512 + t
    long b = row >> 9, t = row & 511;
    *(half8*)(xs16 + ((t << 6) + b) * 1024 + (e & 1023)) = o;  // row t*64+b
  } else if (gid < 4202496) {
    long j = gid - 4194304;
    const float4* p = (const float4*)h0 + j * 2;
    float4 u = p[0], w = p[1];
    half8 o;
    o[0] = (_Float16)u.x; o[1] = (_Float16)u.y; o[2] = (_Float16)u.z; o[3] = (_Float16)u.w;
    o[4] = (_Float16)w.x; o[5] = (_Float16)w.y; o[6] = (_Float16)w.z; o[7] = (_Float16)w.w;
    *(half8*)(hb0 + j * 8) = o;
  } else if (gid < 4210689) {
    flags[gid - 4202496] = 0;  // spread flags [0,4096), spread cnt [4096,8192), tot [8192]
  }
}

// ---------------- transpose [1024][4096] f32 -> [4096][1024] f16 ----------------
__global__ void transpose_k(const float* __restrict__ in, _Float16* __restrict__ outp) {
  __shared__ float s[32][33];
  int bx = blockIdx.x * 32, by = blockIdx.y * 32;
  int tx = threadIdx.x, ty = threadIdx.y;
#pragma unroll
  for (int k = 0; k < 32; k += 8)
    s[ty + k][tx] = in[(long)(by + ty + k) * 4096 + bx + tx];
  __syncthreads();
#pragma unroll
  for (int k = 0; k < 32; k += 8)
    outp[(long)(bx + ty + k) * 1024 + by + tx] = (_Float16)s[tx][ty + k];
}

// ---------------- fused: gemm1 workers + persistent scan ----------------
__global__ __launch_bounds__(256, 1) void fused(const _Float16* __restrict__ xs16,
                                                const _Float16* __restrict__ wxt,
                                                _Float16* __restrict__ xprj,
                                                const _Float16* __restrict__ wht,
                                                const float* __restrict__ bias,
                                                const float* __restrict__ c0,
                                                _Float16* __restrict__ hbuf,
                                                int* __restrict__ flags,
                                                float* __restrict__ out) {
  __shared__ char smem[131072];
  const int tid = threadIdx.x;
  int* const cnt = flags + 4096;
  int* const tot = flags + 8192;

  if (blockIdx.x >= 64) {
    // ---------------- gemm1 tile ----------------
    _Float16* sA = (_Float16*)smem;
    _Float16* sB = (_Float16*)(smem + 8192);
    const int gid = blockIdx.x - 64;
    const int by = gid >> 5, bx = gid & 31;

    // pace: stay <= 48 steps (24 t-groups) ahead of the scan. Bounded wait
    // (timeout) -> liveness even under out-of-order dispatch.
    {
      int it = 0;
      for (;;) {
        int tp = __hip_atomic_load(&flags[0], __ATOMIC_RELAXED, __HIP_MEMORY_SCOPE_AGENT);
        if (tp >= 2 * by - 48 || ++it > 256) break;
        __builtin_amdgcn_s_sleep(64);
      }
    }

    const int w = tid >> 6, l = tid & 63, li = l & 15, q = l >> 4;
    const int wr = w >> 1, wc = w & 1;
    const int m0 = by * 128, n0 = bx * 128;
    floatx4 acc[4][4] = {};
    const _Float16* gA0 = xs16 + (long)(m0 + (w * 16 + li)) * 1024 + q * 8;
    const _Float16* gA1 = xs16 + (long)(m0 + ((4 + w) * 16 + li)) * 1024 + q * 8;
    const _Float16* gB0 = wxt + (long)(n0 + (w * 16 + li)) * 1024 + q * 8;
    const _Float16* gB1 = wxt + (long)(n0 + ((4 + w) * 16 + li)) * 1024 + q * 8;
    _Float16* lA0 = sA + (w * 64) * 8;
    _Float16* lA1 = sA + (256 + w * 64) * 8;
    _Float16* lB0 = sB + (w * 64) * 8;
    _Float16* lB1 = sB + (256 + w * 64) * 8;
    for (int k0 = 0; k0 < 1024; k0 += 32) {
      __syncthreads();
      gll16(gA0 + k0, lA0);
      gll16(gA1 + k0, lA1);
      gll16(gB0 + k0, lB0);
      gll16(gB1 + k0, lB1);
      __syncthreads();
      half8 af[4], bf[4];
      const half8* pA = (const half8*)sA;
      const half8* pB = (const half8*)sB;
#pragma unroll
      for (int i = 0; i < 4; i++) af[i] = pA[(wr * 4 + i) * 64 + l];
#pragma unroll
      for (int j = 0; j < 4; j++) bf[j] = pB[(wc * 4 + j) * 64 + l];
#pragma unroll
      for (int i = 0; i < 4; i++)
#pragma unroll
        for (int j = 0; j < 4; j++)
          acc[i][j] = __builtin_amdgcn_mfma_f32_16x16x32_f16(af[i], bf[j], acc[i][j], 0, 0, 0);
    }
    // C-write, gate-planar scan-consume layout. t = by*2+wr fixed per thread;
    // per (i,j): one dense 512B wave store into plane g_.
    {
      const int t_ = by * 2 + wr;
#pragma unroll
      for (int i = 0; i < 4; i++) {
#pragma unroll
        for (int j = 0; j < 4; j++) {
          int n_ = n0 + wc * 64 + j * 16;       // li excluded (enters lane idx)
          int g_ = n_ >> 10, wg_ = (n_ & 1023) >> 4;
          half4 hv;
          hv[0] = (_Float16)acc[i][j][0];
          hv[1] = (_Float16)acc[i][j][1];
          hv[2] = (_Float16)acc[i][j][2];
          hv[3] = (_Float16)acc[i][j][3];
          *(half4*)(xprj + (long)g_ * XPLANE +
                    (((long)t_ * 64 + wg_) * 256 + (i * 4 + q) * 16 + li) * 4) = hv;
        }
      }
    }
    __syncthreads();  // drains all threads' C stores (vmcnt 0 before barrier)
    if (tid == 0) {
      __builtin_amdgcn_fence(__ATOMIC_RELEASE, "agent");
      __hip_atomic_fetch_add(&cnt[by * 16], 1, __ATOMIC_RELAXED, __HIP_MEMORY_SCOPE_AGENT);
      __hip_atomic_fetch_add(tot, 1, __ATOMIC_RELAXED, __HIP_MEMORY_SCOPE_AGENT);
    }
    return;
  }

  // ---------------- scan (sync chain identical to v5/v7; flags spread) ----------------
  _Float16* sW = (_Float16*)smem;  // [g(4)][kk(32)][lane(64)][8] = 128 KB
  const int wgid = blockIdx.x;     // 0..63
  const int v = tid >> 6;          // wave 0..3
  const int l = tid & 63, li = l & 15, q = l >> 4;
  const int ks = wgid * 16;

  // stage Wh^T slice into LDS once: 8192 x 16B chunks
#pragma unroll 4
  for (int i = 0; i < 32; i++) {
    int c = i * 256 + tid;
    int g = c >> 11, kk = (c >> 6) & 31;
    int cli = c & 15, cq = (c >> 4) & 3;
    gll16(wht + (long)((g << 10) + ks + cli) * 1024 + kk * 32 + cq * 8,
          sW + (long)(c - l) * 8);
  }
  float creg[4];
#pragma unroll
  for (int r = 0; r < 4; r++)
    creg[r] = c0[(long)(v * 16 + q * 4 + r) * 1024 + ks + li];
  float bs[4];
#pragma unroll
  for (int g = 0; g < 4; g++) bs[g] = bias[(g << 10) + ks + li];
  __syncthreads();  // sW resident; last barrier in the kernel

  const half8* pW = (const half8*)sW;
  const int fidx = (4 * l + v) * 16;  // lane l audits wg l, OWN class; 64B-spread
  int xdone = 0;

  for (int t = 0; t < 512; t++) {
    // gate on xproj readiness for this 2-step group (cheap once gemm is ahead)
    if (!xdone && !(t & 1)) {
      const int nb = t >> 1;
      for (;;) {
        int cr = __hip_atomic_load(&cnt[nb * 16], __ATOMIC_RELAXED, __HIP_MEMORY_SCOPE_AGENT);
        if (cr >= 32) break;
        __builtin_amdgcn_s_sleep(16);
      }
      xdone = (__hip_atomic_load(tot, __ATOMIC_RELAXED, __HIP_MEMORY_SCOPE_AGENT) >= 8192);
      __builtin_amdgcn_fence(__ATOMIC_ACQUIRE, "agent");
    }

    // prefetch this lane's xproj: 4 coalesced half4 loads (hidden behind poll)
    const long xbase = (((long)t * 64 + wgid) * 256 + v * 64 + l) * 4;
    half4 xg0 = *(const half4*)(xprj + 0 * XPLANE + xbase);
    half4 xg1 = *(const half4*)(xprj + 1 * XPLANE + xbase);
    half4 xg2 = *(const half4*)(xprj + 2 * XPLANE + xbase);
    half4 xg3 = *(const half4*)(xprj + 3 * XPLANE + xbase);

    // one-shot poll of the 64 same-class wave-flags (each in its own line)
    for (;;) {
      int f = __hip_atomic_load(&flags[fidx], __ATOMIC_RELAXED, __HIP_MEMORY_SCOPE_AGENT);
      if (__all(f >= t)) break;
      __builtin_amdgcn_s_sleep(1);
    }
    __builtin_amdgcn_fence(__ATOMIC_ACQUIRE, "workgroup");  // no hoisting of h loads

    // K-loop: acc[g] += h_t[16v..16v+16][:] @ Wh[:, g*1024+ks..+16]
    const _Float16* hrow = hbuf + (long)t * 65536 + (long)(v * 16 + li) * 1024 + q * 8;
    floatx4 acc[4] = {};
    half8 ap[8];
#pragma unroll
    for (int p = 0; p < 8; p++) ap[p] = *(const half8*)(hrow + p * 32);
#pragma unroll
    for (int kk = 0; kk < 32; kk++) {
      half8 a = ap[kk & 7];
#pragma unroll
      for (int g = 0; g < 4; g++)
        acc[g] = __builtin_amdgcn_mfma_f32_16x16x32_f16(a, pW[((g * 32 + kk) << 6) + l], acc[g], 0, 0, 0);
      if (kk < 24) ap[kk & 7] = *(const half8*)(hrow + (kk + 8) * 32);
    }

    // epilogue: lane-local gates for (b = 16v+q*4+r, col ks+li)
    _Float16* hnext = hbuf + (long)(t + 1) * 65536;
    float hval[4], cval[4];
#pragma unroll
    for (int r = 0; r < 4; r++) {
      float gi = acc[0][r] + (float)xg0[r] + bs[0];
      float gf = acc[1][r] + (float)xg1[r] + bs[1];
      float gg = acc[2][r] + (float)xg2[r] + bs[2];
      float go = acc[3][r] + (float)xg3[r] + bs[3];
      float cN = sigm(gf) * creg[r] + sigm(gi) * tanhfast(gg);
      creg[r] = cN;
      cval[r] = cN;
      float hN = sigm(go) * tanhfast(cN);
      hval[r] = hN;
      int b = v * 16 + q * 4 + r;
      unsigned short hu = __builtin_bit_cast(unsigned short, (_Float16)hN);
      __hip_atomic_store((unsigned short*)hnext + (long)b * 1024 + ks + li, hu,
                         __ATOMIC_RELAXED, __HIP_MEMORY_SCOPE_AGENT);
    }
    __builtin_amdgcn_s_waitcnt(0);  // drains ONLY the 4 h stores (rest consumed)
    if (l == 0)
      __hip_atomic_store(&flags[(4 * wgid + v) * 16], t + 1, __ATOMIC_RELAXED, __HIP_MEMORY_SCOPE_AGENT);

    // slow ys (+ final cT/hT) stores AFTER publishing — off the critical path
#pragma unroll
    for (int r = 0; r < 4; r++) {
      int b = v * 16 + q * 4 + r;
      out[131072 + (long)b * 524288 + (long)t * 1024 + ks + li] = hval[r];
      if (t == 511) {
        out[(long)b * 1024 + ks + li] = cval[r];
        out[65536 + (long)b * 1024 + ks + li] = hval[r];
      }
    }
  }
}

// ---------------- host ----------------
extern "C" void kernel_launch(void* const* d_in, const int* in_sizes, int n_in,
                              void* d_out, int out_size, void* d_ws, size_t ws_size,
                              hipStream_t stream) {
  const float* c0 = (const float*)d_in[0];
  const float* h0 = (const float*)d_in[1];
  const float* xs = (const float*)d_in[2];
  const float* Wx = (const float*)d_in[3];
  const float* Wh = (const float*)d_in[4];
  const float* bias = (const float*)d_in[5];
  float* out = (float*)d_out;

  char* ws = (char*)d_ws;
  size_t off = 0;
  _Float16* xs16 = (_Float16*)(ws + off); off += 67108864;    // 32768x1024 f16 (t-major rows)
  _Float16* wxt  = (_Float16*)(ws + off); off += 8388608;     // 4096x1024 f16
  _Float16* wht  = (_Float16*)(ws + off); off += 8388608;     // 4096x1024 f16
  _Float16* xprj = (_Float16*)(ws + off); off += 268435456;   // [g][t][wg][lane][4] f16
  _Float16* hbuf = (_Float16*)(ws + off); off += 67239936;    // 513x64x1024 f16
  int* flags     = (int*)(ws + off);      off += 36864;       // spread flags/cnt + tot
  if (ws_size < off) return;

  prep_ew<<<16449, 256, 0, stream>>>(xs, h0, xs16, hbuf, flags);
  transpose_k<<<dim3(128, 32), dim3(32, 8), 0, stream>>>(Wx, wxt);
  transpose_k<<<dim3(128, 32), dim3(32, 8), 0, stream>>>(Wh, wht);
  fused<<<8256, 256, 0, stream>>>(xs16, wxt, xprj, wht, bias, c0, hbuf, flags, out);
}